// Round 1
// baseline (3635.119 us; speedup 1.0000x reference)
//
#include <hip/hip_runtime.h>

#define NB 4096
#define T_ 128
#define D_ 128
#define H_ 4
#define HD_ 32

typedef __attribute__((ext_vector_type(8))) short short8;
typedef __attribute__((ext_vector_type(4))) float float4v;

__device__ inline unsigned short f2bf(float f) {
  unsigned int u = __builtin_bit_cast(unsigned int, f);
  u += 0x7fffu + ((u >> 16) & 1u);   // round-to-nearest-even
  return (unsigned short)(u >> 16);
}

// LDS layout (units: unsigned short), total 32000 shorts = 64000 B:
//  [0      .. 17408): region A: phase0 xs[128][128] (32768 B), then per-wave os[8][16][136]
//  [17408  .. 22528): ks[128][40]           (K for current head, B-operand layout [s][e])
//  [22528  .. 26880): wt[32][136]           (W^T stage for Wk/Wq/Wv, then V^T [e][s])
//  [26880  .. 32000): E[8][16][40]          (per-wave C->A layout staging)
//  proj phase: wpT[64][136] at 17408 (overlays ks/wt)

__global__ __launch_bounds__(512, 4) void mha_kernel(
    const float* __restrict__ x,  const float* __restrict__ Wq,
    const float* __restrict__ bq, const float* __restrict__ Wk,
    const float* __restrict__ bk, const float* __restrict__ Wv,
    const float* __restrict__ bv, const float* __restrict__ Wp,
    const float* __restrict__ bp, float* __restrict__ out)
{
  __shared__ __align__(16) unsigned short smem[32000];
  const int tid  = threadIdx.x;
  const int b    = blockIdx.x;
  const int wv_i = tid >> 6;      // wave 0..7, owns q rows [16*wv_i, 16*wv_i+16)
  const int lane = tid & 63;
  const int quad = lane >> 4;     // 0..3
  const int n16  = lane & 15;

  unsigned short* xs  = smem;                          // [128][128]
  unsigned short* osw = smem + wv_i * 2176;            // [16][136] per-wave (overlays xs)
  unsigned short* ks  = smem + 17408;                  // [128][40]
  unsigned short* wt  = smem + 22528;                  // [32][136] (also V^T)
  unsigned short* Ew  = smem + 26880 + wv_i * 640;     // [16][40] per-wave
  unsigned short* wpT = smem + 17408;                  // [64][136] proj phase

  // ---- Phase 0: x[b] -> LDS bf16 ----
  const float4* x4 = (const float4*)(x + (size_t)b * 16384);
  #pragma unroll
  for (int i = 0; i < 8; ++i) {
    float4 v = x4[i * 512 + tid];
    int fl = (i * 512 + tid) * 4;
    xs[fl + 0] = f2bf(v.x); xs[fl + 1] = f2bf(v.y);
    xs[fl + 2] = f2bf(v.z); xs[fl + 3] = f2bf(v.w);
  }
  __syncthreads();

  // per-wave x A-frags: rows [16w,16w+16) x k=[0,128)  (4 frags, kept in regs)
  short8 xfrag[4];
  {
    const unsigned short* base = xs + (wv_i * 16 + n16) * 128 + quad * 8;
    #pragma unroll
    for (int kk = 0; kk < 4; ++kk)
      xfrag[kk] = *(const short8*)(base + kk * 32);
  }
  __syncthreads();   // xs region now free -> os overlay

  // stage a [128][32] fp32 weight slab transposed into wt[e][d] (bf16)
  auto stageWT = [&](const float* Wsrc) {
    #pragma unroll
    for (int i = 0; i < 2; ++i) {
      int g4 = tid + i * 512;                     // 1024 float4s total
      float4 v = ((const float4*)Wsrc)[g4];
      int g = g4 * 4; int d = g >> 5; int e = g & 31;
      wt[(e + 0) * 136 + d] = f2bf(v.x);
      wt[(e + 1) * 136 + d] = f2bf(v.y);
      wt[(e + 2) * 136 + d] = f2bf(v.z);
      wt[(e + 3) * 136 + d] = f2bf(v.w);
    }
  };

  // x @ W (W^T staged in wt) -> two 16-col tiles of C-layout acc
  auto projQKV = [&](float4v acc[2]) {
    #pragma unroll
    for (int nt = 0; nt < 2; ++nt) {
      acc[nt] = (float4v)(0.0f);
      #pragma unroll
      for (int kk = 0; kk < 4; ++kk) {
        short8 bfr = *(const short8*)(wt + (nt * 16 + n16) * 136 + kk * 32 + quad * 8);
        acc[nt] = __builtin_amdgcn_mfma_f32_16x16x32_bf16(xfrag[kk], bfr, acc[nt], 0, 0, 0);
      }
    }
  };

  const float LOG2E_SCALE = 0.08838834764831845f * 1.4426950408889634f; // ctx^-0.5 * log2(e)

  #pragma unroll 1
  for (int h = 0; h < H_; ++h) {
    __syncthreads();                     // prev head's ks/vt fully consumed
    stageWT(Wk + h * 4096);
    __syncthreads();
    float4v kacc[2]; projQKV(kacc);
    #pragma unroll
    for (int nt = 0; nt < 2; ++nt) {
      float bias = bk[h * 32 + nt * 16 + n16];
      #pragma unroll
      for (int r = 0; r < 4; ++r)
        ks[(wv_i * 16 + quad * 4 + r) * 40 + nt * 16 + n16] = f2bf(kacc[nt][r] + bias);
    }
    __syncthreads();                     // wt(Wk) consumed
    stageWT(Wq + h * 4096);
    __syncthreads();
    float4v qacc[2]; projQKV(qacc);
    #pragma unroll
    for (int nt = 0; nt < 2; ++nt) {
      float bias = bq[h * 32 + nt * 16 + n16];
      #pragma unroll
      for (int r = 0; r < 4; ++r)
        Ew[(quad * 4 + r) * 40 + nt * 16 + n16] = f2bf(qacc[nt][r] + bias);
    }
    short8 qfrag = *(const short8*)(Ew + n16 * 40 + quad * 8);  // C->A layout round-trip
    __syncthreads();                     // wt(Wq) consumed
    stageWT(Wv + h * 4096);
    __syncthreads();
    float4v vacc[2]; projQKV(vacc);
    __syncthreads();                     // all waves done reading wt(Wv) before V^T overwrite
    #pragma unroll
    for (int nt = 0; nt < 2; ++nt) {
      float bias = bv[h * 32 + nt * 16 + n16];
      #pragma unroll
      for (int r = 0; r < 4; ++r)        // V^T: vt[e][s]
        wt[(nt * 16 + n16) * 136 + wv_i * 16 + quad * 4 + r] = f2bf(vacc[nt][r] + bias);
    }
    __syncthreads();                     // ks + vt complete

    // ---- S = Q K^T, causal: wave w needs only tiles t <= w ----
    float4v s[8];
    #pragma unroll
    for (int t = 0; t < 8; ++t) {
      if (t <= wv_i) {
        short8 kfr = *(const short8*)(ks + (t * 16 + n16) * 40 + quad * 8);
        s[t] = __builtin_amdgcn_mfma_f32_16x16x32_bf16(qfrag, kfr, (float4v)(0.0f), 0, 0, 0);
      }
    }
    // diagonal tile mask: s > q  <=>  n16 > quad*4+r
    #pragma unroll
    for (int r = 0; r < 4; ++r)
      if (n16 > quad * 4 + r) s[wv_i][r] = -__builtin_inff();

    // ---- softmax over row (row = quad*4+r, spread across 16 lanes x tiles) ----
    float l[4];
    #pragma unroll
    for (int r = 0; r < 4; ++r) {
      float mm = -__builtin_inff();
      #pragma unroll
      for (int t = 0; t < 8; ++t) if (t <= wv_i) mm = fmaxf(mm, s[t][r]);
      #pragma unroll
      for (int off = 8; off >= 1; off >>= 1) mm = fmaxf(mm, __shfl_xor(mm, off, 64));
      float ll = 0.0f;
      #pragma unroll
      for (int t = 0; t < 8; ++t) if (t <= wv_i) {
        float p = exp2f((s[t][r] - mm) * LOG2E_SCALE);
        s[t][r] = p; ll += p;
      }
      #pragma unroll
      for (int off = 8; off >= 1; off >>= 1) ll += __shfl_xor(ll, off, 64);
      l[r] = ll;
    }

    // ---- O = P V (chunks of 32 keys; skip fully-masked chunks) ----
    float4v oacc[2] = {(float4v)(0.0f), (float4v)(0.0f)};
    #pragma unroll
    for (int c = 0; c < 4; ++c) {
      if (2 * c <= wv_i) {
        #pragma unroll
        for (int tt = 0; tt < 2; ++tt) {
          int t = 2 * c + tt;
          #pragma unroll
          for (int r = 0; r < 4; ++r)
            Ew[(quad * 4 + r) * 40 + tt * 16 + n16] =
                (t <= wv_i) ? f2bf(s[t][r]) : (unsigned short)0;
        }
        short8 pfrag = *(const short8*)(Ew + n16 * 40 + quad * 8);
        #pragma unroll
        for (int et = 0; et < 2; ++et) {
          short8 vfr = *(const short8*)(wt + (et * 16 + n16) * 136 + c * 32 + quad * 8);
          oacc[et] = __builtin_amdgcn_mfma_f32_16x16x32_bf16(pfrag, vfr, oacc[et], 0, 0, 0);
        }
      }
    }
    // epilogue: normalize by l, store into per-wave O buffer (bf16, A-layout-ready)
    #pragma unroll
    for (int et = 0; et < 2; ++et) {
      #pragma unroll
      for (int r = 0; r < 4; ++r)
        osw[(quad * 4 + r) * 136 + h * 32 + et * 16 + n16] = f2bf(oacc[et][r] / l[r]);
    }
  }

  // ---- final projection: out = O @ Wp + bp ----
  short8 ofrag[4];
  #pragma unroll
  for (int kk = 0; kk < 4; ++kk)
    ofrag[kk] = *(const short8*)(osw + n16 * 136 + kk * 32 + quad * 8);
  float* outb = out + (size_t)b * 16384;

  #pragma unroll 1
  for (int half = 0; half < 2; ++half) {
    __syncthreads();                    // region B free (prev users done)
    #pragma unroll
    for (int i = 0; i < 4; ++i) {       // stage Wp^T slab: cols [half*64, +64)
      int g4 = tid + i * 512;           // 2048 float4s over [128][64]
      int g = g4 * 4; int c = g >> 6; int dd = g & 63;
      float4 v = *(const float4*)(Wp + c * 128 + half * 64 + dd);
      wpT[(dd + 0) * 136 + c] = f2bf(v.x);
      wpT[(dd + 1) * 136 + c] = f2bf(v.y);
      wpT[(dd + 2) * 136 + c] = f2bf(v.z);
      wpT[(dd + 3) * 136 + c] = f2bf(v.w);
    }
    __syncthreads();
    #pragma unroll
    for (int nt = 0; nt < 4; ++nt) {
      float4v acc = (float4v)(0.0f);
      #pragma unroll
      for (int kk = 0; kk < 4; ++kk) {
        short8 bfr = *(const short8*)(wpT + (nt * 16 + n16) * 136 + kk * 32 + quad * 8);
        acc = __builtin_amdgcn_mfma_f32_16x16x32_bf16(ofrag[kk], bfr, acc, 0, 0, 0);
      }
      int col = half * 64 + nt * 16 + n16;
      float bias = bp[col];
      #pragma unroll
      for (int r = 0; r < 4; ++r)
        outb[(size_t)(wv_i * 16 + quad * 4 + r) * 128 + col] = acc[r] + bias;
    }
  }
}

extern "C" void kernel_launch(void* const* d_in, const int* in_sizes, int n_in,
                              void* d_out, int out_size, void* d_ws, size_t ws_size,
                              hipStream_t stream) {
  const float* x  = (const float*)d_in[0];
  const float* Wq = (const float*)d_in[1];
  const float* bq = (const float*)d_in[2];
  const float* Wk = (const float*)d_in[3];
  const float* bk = (const float*)d_in[4];
  const float* Wv = (const float*)d_in[5];
  const float* bv = (const float*)d_in[6];
  const float* Wp = (const float*)d_in[7];
  const float* bp = (const float*)d_in[8];
  mha_kernel<<<dim3(NB), dim3(512), 0, stream>>>(
      x, Wq, bq, Wk, bk, Wv, bv, Wp, bp, (float*)d_out);
}

// Round 2
// 718.106 us; speedup vs baseline: 5.0621x; 5.0621x over previous
//
#include <hip/hip_runtime.h>

#define NB 4096
#define T_ 128
#define D_ 128
#define H_ 4
#define HD_ 32

typedef __attribute__((ext_vector_type(8))) short short8;
typedef __attribute__((ext_vector_type(4))) float float4v;

__device__ inline unsigned short f2bf(float f) {
  unsigned int u = __builtin_bit_cast(unsigned int, f);
  u += 0x7fffu + ((u >> 16) & 1u);   // round-to-nearest-even
  return (unsigned short)(u >> 16);
}

// LDS layout (units: unsigned short), total 32000 shorts = 64000 B:
//  [0      .. 17408): region A: phase0 xs[128][128] (32768 B), then per-wave os[8][16][136]
//  [17408  .. 22528): ks[128][40]           (K for current head, B-operand layout [s][e])
//  [22528  .. 26880): wt[32][136]           (W^T stage for Wk/Wq/Wv, then V^T [e][s])
//  [26880  .. 32000): E[8][16][40]          (per-wave C->A layout staging)
//  proj phase: wpT[64][136] at 17408 (overlays ks/wt)

__global__ __launch_bounds__(512, 4) void mha_kernel(
    const float* __restrict__ x,  const float* __restrict__ Wq,
    const float* __restrict__ bq, const float* __restrict__ Wk,
    const float* __restrict__ bk, const float* __restrict__ Wv,
    const float* __restrict__ bv, const float* __restrict__ Wp,
    const float* __restrict__ bp, float* __restrict__ out)
{
  __shared__ __align__(16) unsigned short smem[32000];
  const int tid  = threadIdx.x;
  const int b    = blockIdx.x;
  const int wv_i = tid >> 6;      // wave 0..7, owns q rows [16*wv_i, 16*wv_i+16)
  const int lane = tid & 63;
  const int quad = lane >> 4;     // 0..3
  const int n16  = lane & 15;

  unsigned short* xs  = smem;                          // [128][128]
  unsigned short* osw = smem + wv_i * 2176;            // [16][136] per-wave (overlays xs)
  unsigned short* ks  = smem + 17408;                  // [128][40]
  unsigned short* wt  = smem + 22528;                  // [32][136] (also V^T)
  unsigned short* Ew  = smem + 26880 + wv_i * 640;     // [16][40] per-wave
  unsigned short* wpT = smem + 17408;                  // [64][136] proj phase

  // ---- Phase 0: x[b] -> LDS bf16 ----
  const float4* x4 = (const float4*)(x + (size_t)b * 16384);
  #pragma unroll
  for (int i = 0; i < 8; ++i) {
    float4 v = x4[i * 512 + tid];
    int fl = (i * 512 + tid) * 4;
    xs[fl + 0] = f2bf(v.x); xs[fl + 1] = f2bf(v.y);
    xs[fl + 2] = f2bf(v.z); xs[fl + 3] = f2bf(v.w);
  }
  __syncthreads();

  // per-wave x A-frags: rows [16w,16w+16) x k=[0,128)  (4 frags, kept in regs)
  short8 xfrag[4];
  {
    const unsigned short* base = xs + (wv_i * 16 + n16) * 128 + quad * 8;
    #pragma unroll
    for (int kk = 0; kk < 4; ++kk)
      xfrag[kk] = *(const short8*)(base + kk * 32);
  }
  __syncthreads();   // xs region now free -> os overlay

  // stage a [128][32] fp32 weight slab transposed into wt[e][d] (bf16)
  auto stageWT = [&](const float* Wsrc) {
    #pragma unroll
    for (int i = 0; i < 2; ++i) {
      int g4 = tid + i * 512;                     // 1024 float4s total
      float4 v = ((const float4*)Wsrc)[g4];
      int g = g4 * 4; int d = g >> 5; int e = g & 31;
      wt[(e + 0) * 136 + d] = f2bf(v.x);
      wt[(e + 1) * 136 + d] = f2bf(v.y);
      wt[(e + 2) * 136 + d] = f2bf(v.z);
      wt[(e + 3) * 136 + d] = f2bf(v.w);
    }
  };

  // x @ W (W^T staged in wt) -> two 16-col tiles of C-layout acc
  auto projQKV = [&](float4v acc[2]) {
    #pragma unroll
    for (int nt = 0; nt < 2; ++nt) {
      acc[nt] = (float4v)(0.0f);
      #pragma unroll
      for (int kk = 0; kk < 4; ++kk) {
        short8 bfr = *(const short8*)(wt + (nt * 16 + n16) * 136 + kk * 32 + quad * 8);
        acc[nt] = __builtin_amdgcn_mfma_f32_16x16x32_bf16(xfrag[kk], bfr, acc[nt], 0, 0, 0);
      }
    }
  };

  const float LOG2E_SCALE = 0.08838834764831845f * 1.4426950408889634f; // ctx^-0.5 * log2(e)

  #pragma unroll 1
  for (int h = 0; h < H_; ++h) {
    __syncthreads();                     // prev head's ks/vt fully consumed
    stageWT(Wk + h * 4096);
    __syncthreads();
    float4v kacc[2]; projQKV(kacc);
    #pragma unroll
    for (int nt = 0; nt < 2; ++nt) {
      float bias = bk[h * 32 + nt * 16 + n16];
      #pragma unroll
      for (int r = 0; r < 4; ++r)
        ks[(wv_i * 16 + quad * 4 + r) * 40 + nt * 16 + n16] = f2bf(kacc[nt][r] + bias);
    }
    __syncthreads();                     // wt(Wk) consumed
    stageWT(Wq + h * 4096);
    __syncthreads();
    float4v qacc[2]; projQKV(qacc);
    #pragma unroll
    for (int nt = 0; nt < 2; ++nt) {
      float bias = bq[h * 32 + nt * 16 + n16];
      #pragma unroll
      for (int r = 0; r < 4; ++r)
        Ew[(quad * 4 + r) * 40 + nt * 16 + n16] = f2bf(qacc[nt][r] + bias);
    }
    short8 qfrag = *(const short8*)(Ew + n16 * 40 + quad * 8);  // C->A layout round-trip
    __syncthreads();                     // wt(Wq) consumed
    stageWT(Wv + h * 4096);
    __syncthreads();
    float4v vacc[2]; projQKV(vacc);
    __syncthreads();                     // all waves done reading wt(Wv) before V^T overwrite
    #pragma unroll
    for (int nt = 0; nt < 2; ++nt) {
      float bias = bv[h * 32 + nt * 16 + n16];
      #pragma unroll
      for (int r = 0; r < 4; ++r)        // V^T: vt[e][s]
        wt[(nt * 16 + n16) * 136 + wv_i * 16 + quad * 4 + r] = f2bf(vacc[nt][r] + bias);
    }
    __syncthreads();                     // ks + vt complete

    // ---- S = Q K^T, causal: wave w needs only tiles t <= w ----
    // NOTE: all register-array indices are compile-time constants (loop fully
    // unrolled, diagonal mask applied via `t == wv_i` inside the static loop).
    // Dynamic indexing (s[wv_i]) demotes the array to scratch -> 13 GB of
    // spill traffic (R1 post-mortem).
    float4v s[8];
    #pragma unroll
    for (int t = 0; t < 8; ++t) {
      if (t <= wv_i) {
        short8 kfr = *(const short8*)(ks + (t * 16 + n16) * 40 + quad * 8);
        float4v acc = __builtin_amdgcn_mfma_f32_16x16x32_bf16(qfrag, kfr, (float4v)(0.0f), 0, 0, 0);
        if (t == wv_i) {               // diagonal tile: mask s > q  <=>  n16 > quad*4+r
          #pragma unroll
          for (int r = 0; r < 4; ++r)
            if (n16 > quad * 4 + r) acc[r] = -__builtin_inff();
        }
        s[t] = acc;
      }
    }

    // ---- softmax over row (row = quad*4+r, spread across 16 lanes x tiles) ----
    float l[4];
    #pragma unroll
    for (int r = 0; r < 4; ++r) {
      float mm = -__builtin_inff();
      #pragma unroll
      for (int t = 0; t < 8; ++t) if (t <= wv_i) mm = fmaxf(mm, s[t][r]);
      #pragma unroll
      for (int off = 8; off >= 1; off >>= 1) mm = fmaxf(mm, __shfl_xor(mm, off, 64));
      float ll = 0.0f;
      #pragma unroll
      for (int t = 0; t < 8; ++t) if (t <= wv_i) {
        float p = exp2f((s[t][r] - mm) * LOG2E_SCALE);
        s[t][r] = p; ll += p;
      }
      #pragma unroll
      for (int off = 8; off >= 1; off >>= 1) ll += __shfl_xor(ll, off, 64);
      l[r] = ll;
    }

    // ---- O = P V (chunks of 32 keys; skip fully-masked chunks) ----
    float4v oacc[2] = {(float4v)(0.0f), (float4v)(0.0f)};
    #pragma unroll
    for (int c = 0; c < 4; ++c) {
      if (2 * c <= wv_i) {
        #pragma unroll
        for (int tt = 0; tt < 2; ++tt) {
          int t = 2 * c + tt;
          #pragma unroll
          for (int r = 0; r < 4; ++r)
            Ew[(quad * 4 + r) * 40 + tt * 16 + n16] =
                (t <= wv_i) ? f2bf(s[t][r]) : (unsigned short)0;
        }
        short8 pfrag = *(const short8*)(Ew + n16 * 40 + quad * 8);
        #pragma unroll
        for (int et = 0; et < 2; ++et) {
          short8 vfr = *(const short8*)(wt + (et * 16 + n16) * 136 + c * 32 + quad * 8);
          oacc[et] = __builtin_amdgcn_mfma_f32_16x16x32_bf16(pfrag, vfr, oacc[et], 0, 0, 0);
        }
      }
    }
    // epilogue: normalize by l, store into per-wave O buffer (bf16, A-layout-ready)
    #pragma unroll
    for (int et = 0; et < 2; ++et) {
      #pragma unroll
      for (int r = 0; r < 4; ++r)
        osw[(quad * 4 + r) * 136 + h * 32 + et * 16 + n16] = f2bf(oacc[et][r] / l[r]);
    }
  }

  // ---- final projection: out = O @ Wp + bp ----
  short8 ofrag[4];
  #pragma unroll
  for (int kk = 0; kk < 4; ++kk)
    ofrag[kk] = *(const short8*)(osw + n16 * 136 + kk * 32 + quad * 8);
  float* outb = out + (size_t)b * 16384;

  #pragma unroll 1
  for (int half = 0; half < 2; ++half) {
    __syncthreads();                    // region B free (prev users done)
    #pragma unroll
    for (int i = 0; i < 4; ++i) {       // stage Wp^T slab: cols [half*64, +64)
      int g4 = tid + i * 512;           // 2048 float4s over [128][64]
      int g = g4 * 4; int c = g >> 6; int dd = g & 63;
      float4 v = *(const float4*)(Wp + c * 128 + half * 64 + dd);
      wpT[(dd + 0) * 136 + c] = f2bf(v.x);
      wpT[(dd + 1) * 136 + c] = f2bf(v.y);
      wpT[(dd + 2) * 136 + c] = f2bf(v.z);
      wpT[(dd + 3) * 136 + c] = f2bf(v.w);
    }
    __syncthreads();
    #pragma unroll
    for (int nt = 0; nt < 4; ++nt) {
      float4v acc = (float4v)(0.0f);
      #pragma unroll
      for (int kk = 0; kk < 4; ++kk) {
        short8 bfr = *(const short8*)(wpT + (nt * 16 + n16) * 136 + kk * 32 + quad * 8);
        acc = __builtin_amdgcn_mfma_f32_16x16x32_bf16(ofrag[kk], bfr, acc, 0, 0, 0);
      }
      int col = half * 64 + nt * 16 + n16;
      float bias = bp[col];
      #pragma unroll
      for (int r = 0; r < 4; ++r)
        outb[(size_t)(wv_i * 16 + quad * 4 + r) * 128 + col] = acc[r] + bias;
    }
  }
}

extern "C" void kernel_launch(void* const* d_in, const int* in_sizes, int n_in,
                              void* d_out, int out_size, void* d_ws, size_t ws_size,
                              hipStream_t stream) {
  const float* x  = (const float*)d_in[0];
  const float* Wq = (const float*)d_in[1];
  const float* bq = (const float*)d_in[2];
  const float* Wk = (const float*)d_in[3];
  const float* bk = (const float*)d_in[4];
  const float* Wv = (const float*)d_in[5];
  const float* bv = (const float*)d_in[6];
  const float* Wp = (const float*)d_in[7];
  const float* bp = (const float*)d_in[8];
  mha_kernel<<<dim3(NB), dim3(512), 0, stream>>>(
      x, Wq, bq, Wk, bk, Wv, bv, Wp, bp, (float*)d_out);
}